// Round 6
// baseline (1160.001 us; speedup 1.0000x reference)
//
#include <hip/hip_runtime.h>
#include <hip/hip_bf16.h>
#include <math.h>

#define B_ 256
#define T_ 256
#define I_ 2048
#define H_ 128

#define BM 128
#define BK 32
#define NKT (I_ / BK)   // 64 K-tiles

// ---- instrumentation: internal repeats to surface per-kernel counters ----
#define PROJ_REP 3
#define SCAN_REP 6

typedef __attribute__((ext_vector_type(8))) short bf16x8;
typedef __attribute__((ext_vector_type(4))) float f32x4;

static __device__ inline short f2bf(float f) {
    __hip_bfloat16 h = __float2bfloat16(f);
    return *reinterpret_cast<short*>(&h);
}

static __device__ inline bf16x8 pack8(float4 a, float4 b) {
    bf16x8 r;
    r[0] = f2bf(a.x); r[1] = f2bf(a.y); r[2] = f2bf(a.z); r[3] = f2bf(a.w);
    r[4] = f2bf(b.x); r[5] = f2bf(b.y); r[6] = f2bf(b.z); r[7] = f2bf(b.w);
    return r;
}

// ---------------------------------------------------------------------------
// Kernel 1: IDENTICAL to R5 except the whole body repeats PROJ_REP times
// (idempotent: re-computes and re-writes the same xp).
// ---------------------------------------------------------------------------
__global__ __launch_bounds__(256, 2) void proj_mfma(
    const float* __restrict__ x, const float* __restrict__ Wih,
    const float* __restrict__ bih, const float* __restrict__ bhh,
    float* __restrict__ xp)
{
    __shared__ __align__(16) float As[2][BM * BK];
    __shared__ __align__(16) float Bs[2][H_ * BK];

    const int tid  = threadIdx.x;
    const int lane = tid & 63;
    const int wid  = tid >> 6;
    const int wr   = wid >> 1;
    const int wc   = wid & 1;
    const long row0 = (long)blockIdx.x * BM;

    const int srow  = lane >> 3;
    const int sunit = (lane & 7) ^ srow;

    const int fr = lane & 15;
    const int fq = lane >> 4;
    const int rb0 = wid * 32;

    for (int rep = 0; rep < PROJ_REP; ++rep) {
        f32x4 acc[4][4];
        #pragma unroll
        for (int m = 0; m < 4; ++m)
            #pragma unroll
            for (int n = 0; n < 4; ++n)
                acc[m][n] = (f32x4){0.f, 0.f, 0.f, 0.f};

        // prologue: stage tile 0 into buf 0
        #pragma unroll
        for (int i = 0; i < 4; ++i) {
            const int rbase = rb0 + i * 8;
            const float* ga = x   + (row0 + rbase + srow) * I_ + sunit * 4;
            const float* gb = Wih + (long)(rbase + srow) * I_ + sunit * 4;
            __builtin_amdgcn_global_load_lds(
                (const __attribute__((address_space(1))) void*)ga,
                (__attribute__((address_space(3))) void*)&As[0][rbase * BK], 16, 0, 0);
            __builtin_amdgcn_global_load_lds(
                (const __attribute__((address_space(1))) void*)gb,
                (__attribute__((address_space(3))) void*)&Bs[0][rbase * BK], 16, 0, 0);
        }
        __syncthreads();

        int p = 0;
        for (int t = 0; t < NKT; ++t) {
            if (t + 1 < NKT) {
                const int kk = (t + 1) * BK;
                #pragma unroll
                for (int i = 0; i < 4; ++i) {
                    const int rbase = rb0 + i * 8;
                    const float* ga = x   + (row0 + rbase + srow) * I_ + kk + sunit * 4;
                    const float* gb = Wih + (long)(rbase + srow) * I_ + kk + sunit * 4;
                    __builtin_amdgcn_global_load_lds(
                        (const __attribute__((address_space(1))) void*)ga,
                        (__attribute__((address_space(3))) void*)&As[p ^ 1][rbase * BK], 16, 0, 0);
                    __builtin_amdgcn_global_load_lds(
                        (const __attribute__((address_space(1))) void*)gb,
                        (__attribute__((address_space(3))) void*)&Bs[p ^ 1][rbase * BK], 16, 0, 0);
                }
            }
            bf16x8 af[4], bfr[4];
            #pragma unroll
            for (int f = 0; f < 4; ++f) {
                const int ra_ = wr * 64 + f * 16 + fr;
                const float4 a0 = *reinterpret_cast<const float4*>(
                    &As[p][ra_ * BK + (((fq * 2)     ^ (ra_ & 7)) * 4)]);
                const float4 a1 = *reinterpret_cast<const float4*>(
                    &As[p][ra_ * BK + (((fq * 2 + 1) ^ (ra_ & 7)) * 4)]);
                af[f] = pack8(a0, a1);
                const int rb_ = wc * 64 + f * 16 + fr;
                const float4 b0 = *reinterpret_cast<const float4*>(
                    &Bs[p][rb_ * BK + (((fq * 2)     ^ (rb_ & 7)) * 4)]);
                const float4 b1 = *reinterpret_cast<const float4*>(
                    &Bs[p][rb_ * BK + (((fq * 2 + 1) ^ (rb_ & 7)) * 4)]);
                bfr[f] = pack8(b0, b1);
            }
            #pragma unroll
            for (int m = 0; m < 4; ++m)
                #pragma unroll
                for (int n = 0; n < 4; ++n)
                    acc[m][n] = __builtin_amdgcn_mfma_f32_16x16x32_bf16(
                        af[m], bfr[n], acc[m][n], 0, 0, 0);
            __syncthreads();
            p ^= 1;
        }

        #pragma unroll
        for (int n = 0; n < 4; ++n) {
            const int col = wc * 64 + n * 16 + fr;
            const float bn = bih[col] + bhh[col];
            #pragma unroll
            for (int m = 0; m < 4; ++m) {
                const long rbase = row0 + wr * 64 + m * 16 + fq * 4;
                #pragma unroll
                for (int j = 0; j < 4; ++j)
                    xp[(rbase + j) * H_ + col] = acc[m][n][j] + bn;
            }
        }
    }
}

// ---------------------------------------------------------------------------
// Kernel 2: IDENTICAL to R5 except the body repeats SCAN_REP times
// (idempotent: restarts h=0, re-reads xp, rewrites the same out[b]).
// ---------------------------------------------------------------------------
__global__ __launch_bounds__(256) void scan_kernel(
    const float* __restrict__ xp, const float* __restrict__ Whh,
    const float* __restrict__ Wfc, const float* __restrict__ bfc,
    float* __restrict__ out)
{
    __shared__ __align__(16) float hbuf[2][H_];

    const int tid  = threadIdx.x;
    const int lane = tid & 63;
    const int w    = tid >> 6;
    const int j    = w * 32 + (lane & 31);
    const int g    = lane >> 5;
    const int b    = blockIdx.x;

    float Wreg[64];
    {
        const float4* wp = reinterpret_cast<const float4*>(&Whh[(long)j * H_ + g * 64]);
        #pragma unroll
        for (int q = 0; q < 16; ++q) {
            const float4 wv = wp[q];
            Wreg[4*q]   = wv.x; Wreg[4*q+1] = wv.y;
            Wreg[4*q+2] = wv.z; Wreg[4*q+3] = wv.w;
        }
    }
    const float* xprow = xp + (long)b * T_ * H_ + j;

    for (int rep = 0; rep < SCAN_REP; ++rep) {
        __syncthreads();                    // previous rep's FC reads done
        if (tid < H_) hbuf[0][tid] = 0.f;

        float xa = xprow[0 * H_];
        float xb = xprow[1 * H_];
        float xc = xprow[2 * H_];
        float xd = xprow[3 * H_];
        __syncthreads();

        auto body = [&](int t, float xpv) {
            const float4* h4 = reinterpret_cast<const float4*>(&hbuf[t & 1][g * 64]);
            float a0 = 0.f, a1 = 0.f, a2 = 0.f, a3 = 0.f;
            #pragma unroll
            for (int q = 0; q < 16; ++q) {
                const float4 hh = h4[q];
                a0 += hh.x * Wreg[4*q];
                a1 += hh.y * Wreg[4*q+1];
                a2 += hh.z * Wreg[4*q+2];
                a3 += hh.w * Wreg[4*q+3];
            }
            float part = (a0 + a1) + (a2 + a3);
            part += __shfl_xor(part, 32);
            const float pre = part + xpv;
            const float e = __expf(2.f * pre);
            hbuf[(t + 1) & 1][j] = 1.f - 2.f / (e + 1.f);
            __syncthreads();
        };

        for (int t = 0; t < T_; t += 4) {
            float xu;
            xu = xa; if (t + 4 < T_) xa = xprow[(long)(t + 4) * H_];
            body(t + 0, xu);
            xu = xb; if (t + 5 < T_) xb = xprow[(long)(t + 5) * H_];
            body(t + 1, xu);
            xu = xc; if (t + 6 < T_) xc = xprow[(long)(t + 6) * H_];
            body(t + 2, xu);
            xu = xd; if (t + 7 < T_) xd = xprow[(long)(t + 7) * H_];
            body(t + 3, xu);
        }

        if (w == 0) {
            float v = hbuf[0][lane] * Wfc[lane] + hbuf[0][lane + 64] * Wfc[lane + 64];
            #pragma unroll
            for (int off = 32; off > 0; off >>= 1) v += __shfl_down(v, off);
            if (lane == 0) out[b] = v + bfc[0];
        }
    }
}

// ---------------------------------------------------------------------------
extern "C" void kernel_launch(void* const* d_in, const int* in_sizes, int n_in,
                              void* d_out, int out_size, void* d_ws, size_t ws_size,
                              hipStream_t stream)
{
    const float* x   = (const float*)d_in[0];
    const float* Wih = (const float*)d_in[1];
    const float* Whh = (const float*)d_in[2];
    const float* bih = (const float*)d_in[3];
    const float* bhh = (const float*)d_in[4];
    const float* Wfc = (const float*)d_in[5];
    const float* bfc = (const float*)d_in[6];
    float* out = (float*)d_out;
    float* xp  = (float*)d_ws;   // 65536 * 128 floats = 32 MB scratch

    proj_mfma<<<dim3((B_ * T_) / BM), dim3(256), 0, stream>>>(x, Wih, bih, bhh, xp);
    scan_kernel<<<dim3(B_), dim3(256), 0, stream>>>(xp, Whh, Wfc, bfc, out);
}

// Round 7
// 278.942 us; speedup vs baseline: 4.1586x; 4.1586x over previous
//
#include <hip/hip_runtime.h>
#include <hip/hip_bf16.h>
#include <math.h>

#define B_ 256
#define T_ 256
#define I_ 2048
#define H_ 128

#define BM 128
#define BK 32
#define NKT (I_ / BK)   // 64 K-tiles

typedef __attribute__((ext_vector_type(8))) short bf16x8;
typedef __attribute__((ext_vector_type(4))) float f32x4;

static __device__ inline short f2bf(float f) {
    __hip_bfloat16 h = __float2bfloat16(f);
    return *reinterpret_cast<short*>(&h);
}

static __device__ inline bf16x8 pack8(float4 a, float4 b) {
    bf16x8 r;
    r[0] = f2bf(a.x); r[1] = f2bf(a.y); r[2] = f2bf(a.z); r[3] = f2bf(a.w);
    r[4] = f2bf(b.x); r[5] = f2bf(b.y); r[6] = f2bf(b.z); r[7] = f2bf(b.w);
    return r;
}

// bf16-pair unpack (bits only; hi keeps stored RNE rounding exactly)
static __device__ inline float bflo(unsigned u) { return __uint_as_float(u << 16); }
static __device__ inline float bfhi(unsigned u) { return __uint_as_float(u & 0xFFFF0000u); }

// barrier that drains ONLY lgkm (DS) — leaves global prefetch in flight
#define LGKM_BARRIER() do {                                  \
    asm volatile("s_waitcnt lgkmcnt(0)" ::: "memory");       \
    __builtin_amdgcn_sched_barrier(0);                       \
    __builtin_amdgcn_s_barrier();                            \
} while (0)

// ---------------------------------------------------------------------------
// Kernel 1 (UNCHANGED from R5): bf16 MFMA projection, global_load_lds
// staging, dbuf LDS, XOR-swizzle both-sides, 1 barrier/K-step.
// ---------------------------------------------------------------------------
__global__ __launch_bounds__(256, 2) void proj_mfma(
    const float* __restrict__ x, const float* __restrict__ Wih,
    const float* __restrict__ bih, const float* __restrict__ bhh,
    float* __restrict__ xp)
{
    __shared__ __align__(16) float As[2][BM * BK];
    __shared__ __align__(16) float Bs[2][H_ * BK];

    const int tid  = threadIdx.x;
    const int lane = tid & 63;
    const int wid  = tid >> 6;
    const int wr   = wid >> 1;
    const int wc   = wid & 1;
    const long row0 = (long)blockIdx.x * BM;

    const int srow  = lane >> 3;
    const int sunit = (lane & 7) ^ srow;

    f32x4 acc[4][4];
    #pragma unroll
    for (int m = 0; m < 4; ++m)
        #pragma unroll
        for (int n = 0; n < 4; ++n)
            acc[m][n] = (f32x4){0.f, 0.f, 0.f, 0.f};

    const int fr = lane & 15;
    const int fq = lane >> 4;
    const int rb0 = wid * 32;

    #pragma unroll
    for (int i = 0; i < 4; ++i) {
        const int rbase = rb0 + i * 8;
        const float* ga = x   + (row0 + rbase + srow) * I_ + sunit * 4;
        const float* gb = Wih + (long)(rbase + srow) * I_ + sunit * 4;
        __builtin_amdgcn_global_load_lds(
            (const __attribute__((address_space(1))) void*)ga,
            (__attribute__((address_space(3))) void*)&As[0][rbase * BK], 16, 0, 0);
        __builtin_amdgcn_global_load_lds(
            (const __attribute__((address_space(1))) void*)gb,
            (__attribute__((address_space(3))) void*)&Bs[0][rbase * BK], 16, 0, 0);
    }
    __syncthreads();

    int p = 0;
    for (int t = 0; t < NKT; ++t) {
        if (t + 1 < NKT) {
            const int kk = (t + 1) * BK;
            #pragma unroll
            for (int i = 0; i < 4; ++i) {
                const int rbase = rb0 + i * 8;
                const float* ga = x   + (row0 + rbase + srow) * I_ + kk + sunit * 4;
                const float* gb = Wih + (long)(rbase + srow) * I_ + kk + sunit * 4;
                __builtin_amdgcn_global_load_lds(
                    (const __attribute__((address_space(1))) void*)ga,
                    (__attribute__((address_space(3))) void*)&As[p ^ 1][rbase * BK], 16, 0, 0);
                __builtin_amdgcn_global_load_lds(
                    (const __attribute__((address_space(1))) void*)gb,
                    (__attribute__((address_space(3))) void*)&Bs[p ^ 1][rbase * BK], 16, 0, 0);
            }
        }
        bf16x8 af[4], bfr[4];
        #pragma unroll
        for (int f = 0; f < 4; ++f) {
            const int ra_ = wr * 64 + f * 16 + fr;
            const float4 a0 = *reinterpret_cast<const float4*>(
                &As[p][ra_ * BK + (((fq * 2)     ^ (ra_ & 7)) * 4)]);
            const float4 a1 = *reinterpret_cast<const float4*>(
                &As[p][ra_ * BK + (((fq * 2 + 1) ^ (ra_ & 7)) * 4)]);
            af[f] = pack8(a0, a1);
            const int rb_ = wc * 64 + f * 16 + fr;
            const float4 b0 = *reinterpret_cast<const float4*>(
                &Bs[p][rb_ * BK + (((fq * 2)     ^ (rb_ & 7)) * 4)]);
            const float4 b1 = *reinterpret_cast<const float4*>(
                &Bs[p][rb_ * BK + (((fq * 2 + 1) ^ (rb_ & 7)) * 4)]);
            bfr[f] = pack8(b0, b1);
        }
        #pragma unroll
        for (int m = 0; m < 4; ++m)
            #pragma unroll
            for (int n = 0; n < 4; ++n)
                acc[m][n] = __builtin_amdgcn_mfma_f32_16x16x32_bf16(
                    af[m], bfr[n], acc[m][n], 0, 0, 0);
        __syncthreads();
        p ^= 1;
    }

    #pragma unroll
    for (int n = 0; n < 4; ++n) {
        const int col = wc * 64 + n * 16 + fr;
        const float bn = bih[col] + bhh[col];
        #pragma unroll
        for (int m = 0; m < 4; ++m) {
            const long rbase = row0 + wr * 64 + m * 16 + fq * 4;
            #pragma unroll
            for (int j = 0; j < 4; ++j)
                xp[(rbase + j) * H_ + col] = acc[m][n][j] + bn;
        }
    }
}

// ---------------------------------------------------------------------------
// Kernel 2: h broadcast via LDS in PACKED BF16 (halves DS-pipe instrs, the
// measured bottleneck); lgkm-only barrier (xp prefetch stays in flight).
// Structure otherwise as R5: 1 block/row, 4 waves, W_hh fp32 in VGPRs,
// shfl_xor(32) k-half combine, 1 barrier/step, 4-deep xp prefetch.
// ---------------------------------------------------------------------------
__global__ __launch_bounds__(256) void scan_kernel(
    const float* __restrict__ xp, const float* __restrict__ Whh,
    const float* __restrict__ Wfc, const float* __restrict__ bfc,
    float* __restrict__ out)
{
    __shared__ __align__(16) unsigned short hbuf16[2][H_];   // bf16 h, dbuf

    const int tid  = threadIdx.x;
    const int lane = tid & 63;
    const int w    = tid >> 6;
    const int j    = w * 32 + (lane & 31);
    const int g    = lane >> 5;
    const int b    = blockIdx.x;

    float Wreg[64];
    {
        const float4* wp = reinterpret_cast<const float4*>(&Whh[(long)j * H_ + g * 64]);
        #pragma unroll
        for (int q = 0; q < 16; ++q) {
            const float4 wv = wp[q];
            Wreg[4*q]   = wv.x; Wreg[4*q+1] = wv.y;
            Wreg[4*q+2] = wv.z; Wreg[4*q+3] = wv.w;
        }
    }
    if (tid < H_) hbuf16[0][tid] = 0;

    const float* xprow = xp + (long)b * T_ * H_ + j;
    float xa = xprow[0 * H_];
    float xb = xprow[1 * H_];
    float xc = xprow[2 * H_];
    float xd = xprow[3 * H_];
    __syncthreads();

    auto body = [&](int t, float xpv) {
        // broadcast-read own k-half: 64 bf16 = 8 x b128
        const uint4* h4 = reinterpret_cast<const uint4*>(&hbuf16[t & 1][g * 64]);
        float a0 = 0.f, a1 = 0.f, a2 = 0.f, a3 = 0.f;
        #pragma unroll
        for (int q = 0; q < 8; ++q) {
            const uint4 u = h4[q];
            a0 += bflo(u.x) * Wreg[8*q+0];
            a1 += bfhi(u.x) * Wreg[8*q+1];
            a2 += bflo(u.y) * Wreg[8*q+2];
            a3 += bfhi(u.y) * Wreg[8*q+3];
            a0 += bflo(u.z) * Wreg[8*q+4];
            a1 += bfhi(u.z) * Wreg[8*q+5];
            a2 += bflo(u.w) * Wreg[8*q+6];
            a3 += bfhi(u.w) * Wreg[8*q+7];
        }
        float part = (a0 + a1) + (a2 + a3);
        part += __shfl_xor(part, 32);           // combine k-halves in-wave
        const float pre = part + xpv;
        const float e = __expf(2.f * pre);      // tanh = 1 - 2/(e^{2x}+1)
        const float h = 1.f - 2.f / (e + 1.f);
        if (g == 0) {                           // one writer per j
            __hip_bfloat16 hb = __float2bfloat16(h);
            hbuf16[(t + 1) & 1][j] = *reinterpret_cast<unsigned short*>(&hb);
        }
        LGKM_BARRIER();                         // DS-drain only; vmem stays in flight
    };

    for (int t = 0; t < T_; t += 4) {
        float xu;
        xu = xa; if (t + 4 < T_) xa = xprow[(long)(t + 4) * H_];
        body(t + 0, xu);
        xu = xb; if (t + 5 < T_) xb = xprow[(long)(t + 5) * H_];
        body(t + 1, xu);
        xu = xc; if (t + 6 < T_) xc = xprow[(long)(t + 6) * H_];
        body(t + 2, xu);
        xu = xd; if (t + 7 < T_) xd = xprow[(long)(t + 7) * H_];
        body(t + 3, xu);
    }

    // final FC: h_T is in hbuf16[0] (t=255 wrote (255+1)&1 = 0)
    if (w == 0) {
        const unsigned u = reinterpret_cast<const unsigned*>(hbuf16[0])[lane];
        float v = bflo(u) * Wfc[2 * lane] + bfhi(u) * Wfc[2 * lane + 1];
        #pragma unroll
        for (int off = 32; off > 0; off >>= 1) v += __shfl_down(v, off);
        if (lane == 0) out[b] = v + bfc[0];
    }
}

// ---------------------------------------------------------------------------
extern "C" void kernel_launch(void* const* d_in, const int* in_sizes, int n_in,
                              void* d_out, int out_size, void* d_ws, size_t ws_size,
                              hipStream_t stream)
{
    const float* x   = (const float*)d_in[0];
    const float* Wih = (const float*)d_in[1];
    const float* Whh = (const float*)d_in[2];
    const float* bih = (const float*)d_in[3];
    const float* bhh = (const float*)d_in[4];
    const float* Wfc = (const float*)d_in[5];
    const float* bfc = (const float*)d_in[6];
    float* out = (float*)d_out;
    float* xp  = (float*)d_ws;   // 65536 * 128 floats = 32 MB scratch

    proj_mfma<<<dim3((B_ * T_) / BM), dim3(256), 0, stream>>>(x, Wih, bih, bhh, xp);
    scan_kernel<<<dim3(B_), dim3(256), 0, stream>>>(xp, Whh, Wfc, bfc, out);
}

// Round 9
// 222.526 us; speedup vs baseline: 5.2129x; 1.2535x over previous
//
#include <hip/hip_runtime.h>
#include <hip/hip_bf16.h>
#include <math.h>

#define B_ 256
#define T_ 256
#define I_ 2048
#define H_ 128

#define BM 128
#define BK 32
#define NKT (I_ / BK)   // 64 K-tiles

typedef __attribute__((ext_vector_type(8))) short bf16x8;
typedef __attribute__((ext_vector_type(4))) float f32x4;
typedef _Float16 half2v __attribute__((ext_vector_type(2)));

static __device__ inline short f2bf(float f) {
    __hip_bfloat16 h = __float2bfloat16(f);
    return *reinterpret_cast<short*>(&h);
}

static __device__ inline bf16x8 pack8(float4 a, float4 b) {
    bf16x8 r;
    r[0] = f2bf(a.x); r[1] = f2bf(a.y); r[2] = f2bf(a.z); r[3] = f2bf(a.w);
    r[4] = f2bf(b.x); r[5] = f2bf(b.y); r[6] = f2bf(b.z); r[7] = f2bf(b.w);
    return r;
}

// barrier that drains ONLY lgkm (DS) — leaves global prefetch in flight
#define LGKM_BARRIER() do {                                  \
    asm volatile("s_waitcnt lgkmcnt(0)" ::: "memory");       \
    __builtin_amdgcn_sched_barrier(0);                       \
    __builtin_amdgcn_s_barrier();                            \
} while (0)

// ---------------------------------------------------------------------------
// Kernel 1 (UNCHANGED from R5): bf16 MFMA projection, global_load_lds
// staging, dbuf LDS, XOR-swizzle both-sides, 1 barrier/K-step.
// ---------------------------------------------------------------------------
__global__ __launch_bounds__(256, 2) void proj_mfma(
    const float* __restrict__ x, const float* __restrict__ Wih,
    const float* __restrict__ bih, const float* __restrict__ bhh,
    float* __restrict__ xp)
{
    __shared__ __align__(16) float As[2][BM * BK];
    __shared__ __align__(16) float Bs[2][H_ * BK];

    const int tid  = threadIdx.x;
    const int lane = tid & 63;
    const int wid  = tid >> 6;
    const int wr   = wid >> 1;
    const int wc   = wid & 1;
    const long row0 = (long)blockIdx.x * BM;

    const int srow  = lane >> 3;
    const int sunit = (lane & 7) ^ srow;

    f32x4 acc[4][4];
    #pragma unroll
    for (int m = 0; m < 4; ++m)
        #pragma unroll
        for (int n = 0; n < 4; ++n)
            acc[m][n] = (f32x4){0.f, 0.f, 0.f, 0.f};

    const int fr = lane & 15;
    const int fq = lane >> 4;
    const int rb0 = wid * 32;

    #pragma unroll
    for (int i = 0; i < 4; ++i) {
        const int rbase = rb0 + i * 8;
        const float* ga = x   + (row0 + rbase + srow) * I_ + sunit * 4;
        const float* gb = Wih + (long)(rbase + srow) * I_ + sunit * 4;
        __builtin_amdgcn_global_load_lds(
            (const __attribute__((address_space(1))) void*)ga,
            (__attribute__((address_space(3))) void*)&As[0][rbase * BK], 16, 0, 0);
        __builtin_amdgcn_global_load_lds(
            (const __attribute__((address_space(1))) void*)gb,
            (__attribute__((address_space(3))) void*)&Bs[0][rbase * BK], 16, 0, 0);
    }
    __syncthreads();

    int p = 0;
    for (int t = 0; t < NKT; ++t) {
        if (t + 1 < NKT) {
            const int kk = (t + 1) * BK;
            #pragma unroll
            for (int i = 0; i < 4; ++i) {
                const int rbase = rb0 + i * 8;
                const float* ga = x   + (row0 + rbase + srow) * I_ + kk + sunit * 4;
                const float* gb = Wih + (long)(rbase + srow) * I_ + kk + sunit * 4;
                __builtin_amdgcn_global_load_lds(
                    (const __attribute__((address_space(1))) void*)ga,
                    (__attribute__((address_space(3))) void*)&As[p ^ 1][rbase * BK], 16, 0, 0);
                __builtin_amdgcn_global_load_lds(
                    (const __attribute__((address_space(1))) void*)gb,
                    (__attribute__((address_space(3))) void*)&Bs[p ^ 1][rbase * BK], 16, 0, 0);
            }
        }
        bf16x8 af[4], bfr[4];
        #pragma unroll
        for (int f = 0; f < 4; ++f) {
            const int ra_ = wr * 64 + f * 16 + fr;
            const float4 a0 = *reinterpret_cast<const float4*>(
                &As[p][ra_ * BK + (((fq * 2)     ^ (ra_ & 7)) * 4)]);
            const float4 a1 = *reinterpret_cast<const float4*>(
                &As[p][ra_ * BK + (((fq * 2 + 1) ^ (ra_ & 7)) * 4)]);
            af[f] = pack8(a0, a1);
            const int rb_ = wc * 64 + f * 16 + fr;
            const float4 b0 = *reinterpret_cast<const float4*>(
                &Bs[p][rb_ * BK + (((fq * 2)     ^ (rb_ & 7)) * 4)]);
            const float4 b1 = *reinterpret_cast<const float4*>(
                &Bs[p][rb_ * BK + (((fq * 2 + 1) ^ (rb_ & 7)) * 4)]);
            bfr[f] = pack8(b0, b1);
        }
        #pragma unroll
        for (int m = 0; m < 4; ++m)
            #pragma unroll
            for (int n = 0; n < 4; ++n)
                acc[m][n] = __builtin_amdgcn_mfma_f32_16x16x32_bf16(
                    af[m], bfr[n], acc[m][n], 0, 0, 0);
        __syncthreads();
        p ^= 1;
    }

    #pragma unroll
    for (int n = 0; n < 4; ++n) {
        const int col = wc * 64 + n * 16 + fr;
        const float bn = bih[col] + bhh[col];
        #pragma unroll
        for (int m = 0; m < 4; ++m) {
            const long rbase = row0 + wr * 64 + m * 16 + fq * 4;
            #pragma unroll
            for (int j = 0; j < 4; ++j)
                xp[(rbase + j) * H_ + col] = acc[m][n][j] + bn;
        }
    }
}

// ---------------------------------------------------------------------------
// Kernel 2: h in LDS as packed f16 pairs; matvec via v_dot2_f32_f16 (packed
// operands straight off the ds_read — no unpack on the chain); k-half
// combine via __shfl_xor(32) (PROVEN; R8's permlane32_swap with identical
// operands degenerated to a self half-swap -> wrong sums); lgkm-only
// barrier; 4-deep xp prefetch. 1 block/row, 4 waves; thread
// (j = w*32+(l&31), g = l>>5) holds W_hh[j][64g..+63] as 32 f16 pairs.
// ---------------------------------------------------------------------------
__global__ __launch_bounds__(256) void scan_kernel(
    const float* __restrict__ xp, const float* __restrict__ Whh,
    const float* __restrict__ Wfc, const float* __restrict__ bfc,
    float* __restrict__ out)
{
    __shared__ __align__(16) unsigned hpk[2][H_ / 2];   // 64 u32 = 128 f16, dbuf

    const int tid  = threadIdx.x;
    const int lane = tid & 63;
    const int w    = tid >> 6;
    const int j    = w * 32 + (lane & 31);
    const int g    = lane >> 5;
    const int b    = blockIdx.x;

    // W_hh[j][g-half] fp32 -> 32 packed f16 pairs (k-pairs (2q, 2q+1))
    half2v Wh[32];
    {
        const float4* wp = reinterpret_cast<const float4*>(&Whh[(long)j * H_ + g * 64]);
        #pragma unroll
        for (int q = 0; q < 16; ++q) {
            const float4 wv = wp[q];
            half2v p0, p1;
            p0[0] = (_Float16)wv.x; p0[1] = (_Float16)wv.y;
            p1[0] = (_Float16)wv.z; p1[1] = (_Float16)wv.w;
            Wh[2 * q]     = p0;
            Wh[2 * q + 1] = p1;
        }
    }
    if (tid < H_ / 2) hpk[0][tid] = 0u;

    const float* xprow = xp + (long)b * T_ * H_ + j;
    float xa = xprow[0 * H_];
    float xb = xprow[1 * H_];
    float xc = xprow[2 * H_];
    float xd = xprow[3 * H_];
    __syncthreads();

    auto body = [&](int t, float xpv) {
        // own k-half: 32 u32 (64 f16) = 8 x b128, broadcast reads
        const uint4* hp = reinterpret_cast<const uint4*>(&hpk[t & 1][g * 32]);
        float a0 = 0.f, a1 = 0.f, a2 = 0.f, a3 = 0.f;
        #pragma unroll
        for (int q = 0; q < 8; ++q) {
            const uint4 u = hp[q];
            a0 = __builtin_amdgcn_fdot2(__builtin_bit_cast(half2v, u.x), Wh[4*q+0], a0, false);
            a1 = __builtin_amdgcn_fdot2(__builtin_bit_cast(half2v, u.y), Wh[4*q+1], a1, false);
            a2 = __builtin_amdgcn_fdot2(__builtin_bit_cast(half2v, u.z), Wh[4*q+2], a2, false);
            a3 = __builtin_amdgcn_fdot2(__builtin_bit_cast(half2v, u.w), Wh[4*q+3], a3, false);
        }
        float part = (a0 + a1) + (a2 + a3);
        part += __shfl_xor(part, 32);           // combine k-halves (proven)
        const float pre = part + xpv;
        const float e = __expf(2.f * pre);      // tanh = 1 - 2/(e^{2x}+1)
        const float h = 1.f - 2.f / (e + 1.f);
        if (g == 0) {                           // one writer per j (b16, 2-way free)
            reinterpret_cast<unsigned short*>(&hpk[(t + 1) & 1][0])[j] =
                __builtin_bit_cast(unsigned short, (_Float16)h);
        }
        LGKM_BARRIER();                         // DS-drain only; vmem stays in flight
    };

    for (int t = 0; t < T_; t += 4) {
        float xu;
        xu = xa; if (t + 4 < T_) xa = xprow[(long)(t + 4) * H_];
        body(t + 0, xu);
        xu = xb; if (t + 5 < T_) xb = xprow[(long)(t + 5) * H_];
        body(t + 1, xu);
        xu = xc; if (t + 6 < T_) xc = xprow[(long)(t + 6) * H_];
        body(t + 2, xu);
        xu = xd; if (t + 7 < T_) xd = xprow[(long)(t + 7) * H_];
        body(t + 3, xu);
    }

    // final FC: h_T is in hpk[0] (t=255 wrote (255+1)&1 = 0)
    if (w == 0) {
        const unsigned u = hpk[0][lane];        // pair h[2l], h[2l+1]
        const half2v hh = __builtin_bit_cast(half2v, u);
        float v = (float)hh[0] * Wfc[2 * lane] + (float)hh[1] * Wfc[2 * lane + 1];
        #pragma unroll
        for (int off = 32; off > 0; off >>= 1) v += __shfl_down(v, off);
        if (lane == 0) out[b] = v + bfc[0];
    }
}

// ---------------------------------------------------------------------------
extern "C" void kernel_launch(void* const* d_in, const int* in_sizes, int n_in,
                              void* d_out, int out_size, void* d_ws, size_t ws_size,
                              hipStream_t stream)
{
    const float* x   = (const float*)d_in[0];
    const float* Wih = (const float*)d_in[1];
    const float* Whh = (const float*)d_in[2];
    const float* bih = (const float*)d_in[3];
    const float* bhh = (const float*)d_in[4];
    const float* Wfc = (const float*)d_in[5];
    const float* bfc = (const float*)d_in[6];
    float* out = (float*)d_out;
    float* xp  = (float*)d_ws;   // 65536 * 128 floats = 32 MB scratch

    proj_mfma<<<dim3((B_ * T_) / BM), dim3(256), 0, stream>>>(x, Wih, bih, bhh, xp);
    scan_kernel<<<dim3(B_), dim3(256), 0, stream>>>(xp, Whh, Wfc, bfc, out);
}